// Round 2
// baseline (781.502 us; speedup 1.0000x reference)
//
#include <hip/hip_runtime.h>

typedef unsigned short u16;
typedef unsigned int   u32;

#define N_NODES 100000

typedef short frag8 __attribute__((ext_vector_type(8)));
typedef float f32x4 __attribute__((ext_vector_type(4)));

__device__ __forceinline__ float bf2f(u16 h) {
    union { u32 u; float f; } c; c.u = ((u32)h) << 16; return c.f;
}
__device__ __forceinline__ u16 f2bf(float f) {
    union { float f; u32 u; } c; c.f = f;
    u32 u = c.u;
    return (u16)((u + 0x7FFFu + ((u >> 16) & 1u)) >> 16);
}

union U8 { frag8 f; u16 h[8]; };

// ---------------- edge-index layout detect (int32 vs int64) ----------------
// int64 little-endian with values < 2^31: every odd 32-bit word is 0.
__global__ void detect_kernel(const int* __restrict__ ei, int* __restrict__ flag, int E) {
    int any = 0;
    int lim = min(2048, 2 * E);
    for (int i = 1 + 2 * (int)threadIdx.x; i < lim; i += 128) any |= ei[i];
    unsigned long long b = __ballot(any != 0);
    if (threadIdx.x == 0) *flag = (b != 0ULL) ? 1 : 0;  // 1 => int32 layout
}

// ---------------- CSR build ----------------
__global__ void hist_kernel(const int* __restrict__ ei, int* __restrict__ cnt,
                            const int* __restrict__ flag, int E) {
    int e = blockIdx.x * blockDim.x + threadIdx.x;
    if (e >= E) return;
    int is32 = *flag;
    int d = is32 ? ei[E + e] : ei[2 * (E + (long long)e)];
    if ((u32)d < (u32)N_NODES) atomicAdd(&cnt[d], 1);
}

__global__ void scan1_kernel(const int* __restrict__ cnt, int* __restrict__ row,
                             int* __restrict__ part, int n) {
    __shared__ int lds[1024];
    int t = threadIdx.x, g = blockIdx.x * 1024 + t;
    int v = (g < n) ? cnt[g] : 0;
    lds[t] = v;
    __syncthreads();
    for (int off = 1; off < 1024; off <<= 1) {
        int x = (t >= off) ? lds[t - off] : 0;
        __syncthreads();
        lds[t] += x;
        __syncthreads();
    }
    if (g < n) row[g] = lds[t] - v;           // exclusive
    if (t == 1023) part[blockIdx.x] = lds[t]; // block total
}

__global__ void scan2_kernel(int* __restrict__ part, int nb) {
    if (threadIdx.x == 0 && blockIdx.x == 0) {
        int run = 0;
        for (int i = 0; i < nb; ++i) { int v = part[i]; part[i] = run; run += v; }
    }
}

__global__ void scan3_kernel(int* __restrict__ row, const int* __restrict__ part,
                             int n, int E) {
    int g = blockIdx.x * 1024 + threadIdx.x;
    if (g < n) row[g] += part[blockIdx.x];
    if (g == 0) row[n] = E;
}

// uses cnt as the fill counter (atomicSub); cnt ends at 0, re-memset next launch
__global__ void scatter_kernel(const int* __restrict__ ei, const int* __restrict__ row,
                               int* __restrict__ cnt, int* __restrict__ csr,
                               const int* __restrict__ flag, int E) {
    int e = blockIdx.x * blockDim.x + threadIdx.x;
    if (e >= E) return;
    int is32 = *flag;
    int s = is32 ? ei[e]     : ei[2 * (long long)e];
    int d = is32 ? ei[E + e] : ei[2 * (E + (long long)e)];
    if ((u32)d >= (u32)N_NODES) return;
    int idx = atomicSub(&cnt[d], 1) - 1;
    int pos = row[d] + idx;
    csr[pos] = ((u32)s < (u32)N_NODES) ? s : 0;
}

// ---------------- weight split: W(fp32) -> bf16 hi + bf16 lo planes ----------------
__global__ void wsplit_kernel(const float* __restrict__ W, u16* __restrict__ hi,
                              u16* __restrict__ lo, int n) {
    int i = blockIdx.x * 256 + threadIdx.x;
    if (i >= n) return;
    float v = W[i];
    u16 h = f2bf(v);
    hi[i] = h;
    lo[i] = f2bf(v - bf2f(h));
}

// ---------------- mean aggregation over CSR (fp32 rows -> bf16 mean) ----------------
// MODE 0: plain mean. MODE 1: BN affine folded in, deg==0 -> exact 0.
template <int MODE>
__global__ __launch_bounds__(256) void agg_kernel(
    const float* __restrict__ X, const int* __restrict__ rowstart,
    const int* __restrict__ csr, u16* __restrict__ out,
    const float* __restrict__ bnp) {
    const int wid = (blockIdx.x * 256 + threadIdx.x) >> 6;
    const int lane = threadIdx.x & 63;
    if (wid >= N_NODES) return;
    const int s = rowstart[wid];
    const int e = rowstart[wid + 1];
    const float2* Xf = (const float2*)X;
    float ax = 0.f, ay = 0.f;
    int i = s;
    for (; i + 4 <= e; i += 4) {
        int i0 = csr[i], i1 = csr[i + 1], i2 = csr[i + 2], i3 = csr[i + 3];
        float2 v0 = Xf[(size_t)i0 * 64 + lane];
        float2 v1 = Xf[(size_t)i1 * 64 + lane];
        float2 v2 = Xf[(size_t)i2 * 64 + lane];
        float2 v3 = Xf[(size_t)i3 * 64 + lane];
        ax += (v0.x + v1.x) + (v2.x + v3.x);
        ay += (v0.y + v1.y) + (v2.y + v3.y);
    }
    for (; i < e; ++i) {
        float2 v0 = Xf[(size_t)csr[i] * 64 + lane];
        ax += v0.x; ay += v0.y;
    }
    const int deg = e - s;
    const float inv = 1.0f / (float)max(deg, 1);
    float mx = ax * inv, my = ay * inv;
    if (MODE == 1) {
        if (deg > 0) {
            const int f0 = 2 * lane;
            mx = mx * bnp[f0]     + bnp[128 + f0];
            my = my * bnp[f0 + 1] + bnp[128 + f0 + 1];
        } else { mx = 0.f; my = 0.f; }
    }
    ((u32*)out)[(size_t)wid * 64 + lane] = (u32)f2bf(mx) | ((u32)f2bf(my) << 16);
}

// ---------------- fused GEMM: out = A1*Wl^T + b + f(A2)*Wr^T, then L2-normalize ----
// A1 bf16 (mean), A2 fp32 (x or rh; MODE 1 applies BN affine to A2 on the fly).
// Split-bf16 MFMA: a1*(Wlh+Wll) + (a2h+a2l)*Wrh + a2h*Wrl  (~2^-17 rel precision).
// MODE 0: +ReLU, fp32 out (rh), per-feature BN sum/sumsq. MODE 1: fp32 out (final).
template <int MODE>
__global__ __launch_bounds__(256) void gemm_kernel(
    const u16* __restrict__ A1bf, const float* A2f,
    const u16* __restrict__ Wlh, const u16* __restrict__ Wll,
    const u16* __restrict__ Wrh, const u16* __restrict__ Wrl,
    const float* __restrict__ bias, float* out,
    float* __restrict__ bnsums, const float* __restrict__ bnp) {
    __shared__ float tile[4][16 * 132];
    __shared__ float ldsbn[256];
    __shared__ float ldsp[256];
    const int tid = threadIdx.x;
    const int lane = tid & 63;
    const int wv = tid >> 6;
    const int col = lane & 15;
    const int quad = lane >> 4;
    if (MODE == 0) ldsbn[tid] = 0.f;
    if (MODE == 1) ldsp[tid] = bnp[tid];
    __syncthreads();

    const int nbase = (blockIdx.x * 4 + wv) * 16;
    const bool active = (nbase < N_NODES);  // N % 16 == 0 -> active tiles are full

    f32x4 acc[8];
#pragma unroll
    for (int ft = 0; ft < 8; ++ft) acc[ft] = (f32x4){0.f, 0.f, 0.f, 0.f};
    float v[8][4];

    if (active) {
        const int arow = nbase + col;
#pragma unroll
        for (int ks = 0; ks < 4; ++ks) {
            const int k0 = ks * 32 + quad * 8;
            frag8 a1 = *(const frag8*)(A1bf + (size_t)arow * 128 + k0);
            const float4* ap = (const float4*)(A2f + (size_t)arow * 128 + k0);
            float4 q0 = ap[0], q1 = ap[1];
            float av[8] = {q0.x, q0.y, q0.z, q0.w, q1.x, q1.y, q1.z, q1.w};
            if (MODE == 1) {
#pragma unroll
                for (int j = 0; j < 8; ++j)
                    av[j] = av[j] * ldsp[k0 + j] + ldsp[128 + k0 + j];
            }
            U8 a2h, a2l;
#pragma unroll
            for (int j = 0; j < 8; ++j) {
                u16 h = f2bf(av[j]);
                a2h.h[j] = h;
                a2l.h[j] = f2bf(av[j] - bf2f(h));
            }
#pragma unroll
            for (int ft = 0; ft < 8; ++ft) {
                const size_t off = (size_t)(ft * 16 + col) * 128 + k0;
                frag8 blh = *(const frag8*)(Wlh + off);
                frag8 bll = *(const frag8*)(Wll + off);
                frag8 brh = *(const frag8*)(Wrh + off);
                frag8 brl = *(const frag8*)(Wrl + off);
                acc[ft] = __builtin_amdgcn_mfma_f32_16x16x32_bf16(a1, blh, acc[ft], 0, 0, 0);
                acc[ft] = __builtin_amdgcn_mfma_f32_16x16x32_bf16(a1, bll, acc[ft], 0, 0, 0);
                acc[ft] = __builtin_amdgcn_mfma_f32_16x16x32_bf16(a2h.f, brh, acc[ft], 0, 0, 0);
                acc[ft] = __builtin_amdgcn_mfma_f32_16x16x32_bf16(a2l.f, brh, acc[ft], 0, 0, 0);
                acc[ft] = __builtin_amdgcn_mfma_f32_16x16x32_bf16(a2h.f, brl, acc[ft], 0, 0, 0);
            }
        }
        // bias + row sum-of-squares (C/D layout: row = quad*4 + r, col = lane&15)
        float ss[4] = {0.f, 0.f, 0.f, 0.f};
#pragma unroll
        for (int ft = 0; ft < 8; ++ft) {
            const float bv = bias[ft * 16 + col];
#pragma unroll
            for (int r = 0; r < 4; ++r) {
                float t = acc[ft][r] + bv;
                v[ft][r] = t;
                ss[r] += t * t;
            }
        }
#pragma unroll
        for (int m = 1; m <= 8; m <<= 1) {
#pragma unroll
            for (int r = 0; r < 4; ++r) ss[r] += __shfl_xor(ss[r], m, 64);
        }
        float invn[4];
#pragma unroll
        for (int r = 0; r < 4; ++r) invn[r] = 1.0f / fmaxf(sqrtf(ss[r]), 1e-12f);
#pragma unroll
        for (int ft = 0; ft < 8; ++ft) {
#pragma unroll
            for (int r = 0; r < 4; ++r) {
                float t = v[ft][r] * invn[r];
                if (MODE == 0) t = fmaxf(t, 0.f);
                v[ft][r] = t;
                tile[wv][(quad * 4 + r) * 132 + ft * 16 + col] = t;
            }
        }
        if (MODE == 0) {
#pragma unroll
            for (int ft = 0; ft < 8; ++ft) {
                float s1 = (v[ft][0] + v[ft][1]) + (v[ft][2] + v[ft][3]);
                float s2 = (v[ft][0] * v[ft][0] + v[ft][1] * v[ft][1]) +
                           (v[ft][2] * v[ft][2] + v[ft][3] * v[ft][3]);
                s1 += __shfl_xor(s1, 16, 64); s1 += __shfl_xor(s1, 32, 64);
                s2 += __shfl_xor(s2, 16, 64); s2 += __shfl_xor(s2, 32, 64);
                if (quad == 0) {
                    atomicAdd(&ldsbn[ft * 16 + col], s1);
                    atomicAdd(&ldsbn[128 + ft * 16 + col], s2);
                }
            }
        }
    }
    __syncthreads();
    if (active) {
        float2* orow = (float2*)out;
#pragma unroll
        for (int r = 0; r < 16; ++r) {
            float x0 = tile[wv][r * 132 + 2 * lane];
            float x1 = tile[wv][r * 132 + 2 * lane + 1];
            orow[(size_t)(nbase + r) * 64 + lane] = make_float2(x0, x1);
        }
    }
    if (MODE == 0) atomicAdd(&bnsums[tid], ldsbn[tid]);
}

// ---------------- BN finalize: scale/shift from sums ----------------
__global__ void bnfin_kernel(const float* __restrict__ sums, const float* __restrict__ gamma,
                             const float* __restrict__ beta, float* __restrict__ bnp) {
    int f = threadIdx.x;
    if (f >= 128) return;
    const float invN = 1.0f / (float)N_NODES;
    float mu = sums[f] * invN;
    float var = sums[128 + f] * invN - mu * mu;
    float sc = gamma[f] * rsqrtf(fmaxf(var, 0.f) + 1e-5f);
    bnp[f] = sc;
    bnp[128 + f] = beta[f] - mu * sc;
}

extern "C" void kernel_launch(void* const* d_in, const int* in_sizes, int n_in,
                              void* d_out, int out_size, void* d_ws, size_t ws_size,
                              hipStream_t stream) {
    const int N = N_NODES;
    const int E = in_sizes[1] / 2;

    const float* x     = (const float*)d_in[0];
    const int*   ei    = (const int*)d_in[1];
    const float* Wl1   = (const float*)d_in[2];
    const float* bl1   = (const float*)d_in[3];
    const float* Wr1   = (const float*)d_in[4];
    const float* gamma = (const float*)d_in[5];
    const float* beta  = (const float*)d_in[6];
    const float* Wl2   = (const float*)d_in[7];
    const float* bl2   = (const float*)d_in[8];
    const float* Wr2   = (const float*)d_in[9];
    float* outp = (float*)d_out;  // also serves as rh (layer-1 activations, fp32)

    char* ws = (char*)d_ws;
    size_t off = 0;
    auto alloc = [&](size_t b) { size_t r = off; off += (b + 255) & ~(size_t)255; return r; };
    int*   flag     = (int*)  (ws + alloc(4));
    int*   cnt      = (int*)  (ws + alloc((size_t)N * 4));
    int*   rowstart = (int*)  (ws + alloc((size_t)(N + 1) * 4));
    int*   partials = (int*)  (ws + alloc(1024));
    int*   csr      = (int*)  (ws + alloc((size_t)E * 4));
    float* bnsums   = (float*)(ws + alloc(256 * 4));
    float* bnp      = (float*)(ws + alloc(256 * 4));
    u16*   w1lh     = (u16*)  (ws + alloc(16384 * 2));
    u16*   w1ll     = (u16*)  (ws + alloc(16384 * 2));
    u16*   w1rh     = (u16*)  (ws + alloc(16384 * 2));
    u16*   w1rl     = (u16*)  (ws + alloc(16384 * 2));
    u16*   w2lh     = (u16*)  (ws + alloc(16384 * 2));
    u16*   w2ll     = (u16*)  (ws + alloc(16384 * 2));
    u16*   w2rh     = (u16*)  (ws + alloc(16384 * 2));
    u16*   w2rl     = (u16*)  (ws + alloc(16384 * 2));
    u16*   meanbf   = (u16*)  (ws + alloc((size_t)N * 128 * 2));  // ~33 MB total

    hipMemsetAsync(cnt, 0, (size_t)N * 4, stream);
    hipMemsetAsync(bnsums, 0, 256 * 4, stream);

    detect_kernel<<<1, 64, 0, stream>>>(ei, flag, E);
    hist_kernel<<<(E + 255) / 256, 256, 0, stream>>>(ei, cnt, flag, E);
    const int nb = (N + 1023) / 1024;
    scan1_kernel<<<nb, 1024, 0, stream>>>(cnt, rowstart, partials, N);
    scan2_kernel<<<1, 64, 0, stream>>>(partials, nb);
    scan3_kernel<<<nb, 1024, 0, stream>>>(rowstart, partials, N, E);
    scatter_kernel<<<(E + 255) / 256, 256, 0, stream>>>(ei, rowstart, cnt, csr, flag, E);

    wsplit_kernel<<<64, 256, 0, stream>>>(Wl1, w1lh, w1ll, 16384);
    wsplit_kernel<<<64, 256, 0, stream>>>(Wr1, w1rh, w1rl, 16384);
    wsplit_kernel<<<64, 256, 0, stream>>>(Wl2, w2lh, w2ll, 16384);
    wsplit_kernel<<<64, 256, 0, stream>>>(Wr2, w2rh, w2rl, 16384);

    // conv1: mean-agg(x) -> GEMM(+bias, L2norm, ReLU, BN partial sums); rh -> d_out
    agg_kernel<0><<<(N + 3) / 4, 256, 0, stream>>>(x, rowstart, csr, meanbf, nullptr);
    gemm_kernel<0><<<(N + 63) / 64, 256, 0, stream>>>(meanbf, x, w1lh, w1ll, w1rh, w1rl,
                                                      bl1, outp, bnsums, nullptr);
    bnfin_kernel<<<1, 128, 0, stream>>>(bnsums, gamma, beta, bnp);
    // conv2: mean-agg(BN(rh)) -> GEMM(+bias, L2norm) -> d_out
    agg_kernel<1><<<(N + 3) / 4, 256, 0, stream>>>(outp, rowstart, csr, meanbf, bnp);
    gemm_kernel<1><<<(N + 63) / 64, 256, 0, stream>>>(meanbf, outp, w2lh, w2ll, w2rh, w2rl,
                                                      bl2, outp, nullptr, bnp);
}

// Round 3
// 553.605 us; speedup vs baseline: 1.4117x; 1.4117x over previous
//
#include <hip/hip_runtime.h>

typedef unsigned short u16;
typedef unsigned int   u32;

#define N_NODES 100000

typedef short frag8 __attribute__((ext_vector_type(8)));
typedef float f32x4 __attribute__((ext_vector_type(4)));

__device__ __forceinline__ float bf2f(u16 h) {
    union { u32 u; float f; } c; c.u = ((u32)h) << 16; return c.f;
}
__device__ __forceinline__ u16 f2bf(float f) {
    union { float f; u32 u; } c; c.f = f;
    u32 u = c.u;
    return (u16)((u + 0x7FFFu + ((u >> 16) & 1u)) >> 16);
}
__device__ __forceinline__ float2 bfx2(u32 u) {
    union { u32 u; float f; } lo, hi;
    lo.u = u << 16; hi.u = u & 0xFFFF0000u;
    return make_float2(lo.f, hi.f);
}
__device__ __forceinline__ u32 packbf(float a, float b) {
    return (u32)f2bf(a) | ((u32)f2bf(b) << 16);
}

union U8 { frag8 f; u16 h[8]; };

// ---------------- edge-index layout detect (int32 vs int64) ----------------
__global__ void detect_kernel(const int* __restrict__ ei, int* __restrict__ flag, int E) {
    int any = 0;
    int lim = min(2048, 2 * E);
    for (int i = 1 + 2 * (int)threadIdx.x; i < lim; i += 128) any |= ei[i];
    unsigned long long b = __ballot(any != 0);
    if (threadIdx.x == 0) *flag = (b != 0ULL) ? 1 : 0;  // 1 => int32 layout
}

// ---------------- CSR build ----------------
__global__ void hist_kernel(const int* __restrict__ ei, int* __restrict__ cnt,
                            const int* __restrict__ flag, int E) {
    int e = blockIdx.x * blockDim.x + threadIdx.x;
    if (e >= E) return;
    int is32 = *flag;
    int d = is32 ? ei[E + e] : ei[2 * (E + (long long)e)];
    if ((u32)d < (u32)N_NODES) atomicAdd(&cnt[d], 1);
}

__global__ void scan1_kernel(const int* __restrict__ cnt, int* __restrict__ row,
                             int* __restrict__ part, int n) {
    __shared__ int lds[1024];
    int t = threadIdx.x, g = blockIdx.x * 1024 + t;
    int v = (g < n) ? cnt[g] : 0;
    lds[t] = v;
    __syncthreads();
    for (int off = 1; off < 1024; off <<= 1) {
        int x = (t >= off) ? lds[t - off] : 0;
        __syncthreads();
        lds[t] += x;
        __syncthreads();
    }
    if (g < n) row[g] = lds[t] - v;           // exclusive
    if (t == 1023) part[blockIdx.x] = lds[t]; // block total
}

// parallel exclusive scan over <=1024 block partials (one block)
__global__ void scan2_kernel(int* __restrict__ part, int nb) {
    __shared__ int lds[1024];
    int t = threadIdx.x;
    int v = (t < nb) ? part[t] : 0;
    lds[t] = v;
    __syncthreads();
    for (int off = 1; off < 1024; off <<= 1) {
        int x = (t >= off) ? lds[t - off] : 0;
        __syncthreads();
        lds[t] += x;
        __syncthreads();
    }
    if (t < nb) part[t] = lds[t] - v;
}

__global__ void scan3_kernel(int* __restrict__ row, const int* __restrict__ part,
                             int n, int E) {
    int g = blockIdx.x * 1024 + threadIdx.x;
    if (g < n) row[g] += part[blockIdx.x];
    if (g == 0) row[n] = E;
}

// uses cnt as the fill counter (atomicSub); cnt ends at 0 (re-memset next launch)
__global__ void scatter_kernel(const int* __restrict__ ei, const int* __restrict__ row,
                               int* __restrict__ cnt, int* __restrict__ csr,
                               const int* __restrict__ flag, int E) {
    int e = blockIdx.x * blockDim.x + threadIdx.x;
    if (e >= E) return;
    int is32 = *flag;
    int s = is32 ? ei[e]     : ei[2 * (long long)e];
    int d = is32 ? ei[E + e] : ei[2 * (E + (long long)e)];
    if ((u32)d >= (u32)N_NODES) return;
    int idx = atomicSub(&cnt[d], 1) - 1;
    csr[row[d] + idx] = ((u32)s < (u32)N_NODES) ? s : 0;
}

// ---------------- weight split: W(fp32) -> bf16 hi + bf16 lo planes ----------------
__global__ void wsplit_kernel(const float* __restrict__ W, u16* __restrict__ hi,
                              u16* __restrict__ lo, int n) {
    int i = blockIdx.x * 256 + threadIdx.x;
    if (i >= n) return;
    float v = W[i];
    u16 h = f2bf(v);
    hi[i] = h;
    lo[i] = f2bf(v - bf2f(h));
}

// ---------------- x -> bf16 hi plane (gather source) ----------------
__global__ void xtobf_kernel(const float* __restrict__ X, u16* __restrict__ out, int n2) {
    int i = blockIdx.x * 256 + threadIdx.x;
    if (i >= n2) return;
    float2 v = ((const float2*)X)[i];
    ((u32*)out)[i] = packbf(v.x, v.y);
}

// ---------------- mean aggregation over CSR (bf16 rows -> bf16 mean) ----------------
// MODE 0: plain mean. MODE 1: BN affine folded in, deg==0 -> exact 0.
template <int MODE>
__global__ __launch_bounds__(256) void agg_kernel(
    const u16* __restrict__ X, const int* __restrict__ rowstart,
    const int* __restrict__ csr, u16* __restrict__ out,
    const float* __restrict__ bnp) {
    const int wid = (blockIdx.x * 256 + threadIdx.x) >> 6;
    const int lane = threadIdx.x & 63;
    if (wid >= N_NODES) return;
    const int s = rowstart[wid];
    const int e = rowstart[wid + 1];
    const u32* Xu = (const u32*)X;
    float ax = 0.f, ay = 0.f;
    int i = s;
    for (; i + 4 <= e; i += 4) {
        int i0 = csr[i], i1 = csr[i + 1], i2 = csr[i + 2], i3 = csr[i + 3];
        float2 v0 = bfx2(Xu[(size_t)i0 * 64 + lane]);
        float2 v1 = bfx2(Xu[(size_t)i1 * 64 + lane]);
        float2 v2 = bfx2(Xu[(size_t)i2 * 64 + lane]);
        float2 v3 = bfx2(Xu[(size_t)i3 * 64 + lane]);
        ax += (v0.x + v1.x) + (v2.x + v3.x);
        ay += (v0.y + v1.y) + (v2.y + v3.y);
    }
    for (; i < e; ++i) {
        float2 v0 = bfx2(Xu[(size_t)csr[i] * 64 + lane]);
        ax += v0.x; ay += v0.y;
    }
    const int deg = e - s;
    const float inv = 1.0f / (float)max(deg, 1);
    float mx = ax * inv, my = ay * inv;
    if (MODE == 1) {
        if (deg > 0) {
            const int f0 = 2 * lane;
            mx = mx * bnp[f0]     + bnp[128 + f0];
            my = my * bnp[f0 + 1] + bnp[128 + f0 + 1];
        } else { mx = 0.f; my = 0.f; }
    }
    ((u32*)out)[(size_t)wid * 64 + lane] = packbf(mx, my);
}

// ---------------- fused GEMM with 4x weight reuse (MT=4 node tiles / wave) --------
// GM 0 (layer 1): A1=meanbf(bf16), A2=x(fp32, split in VALU), 5 MFMAs/step,
//                 epilogue: +bias, L2norm, ReLU, BN sums, write bf16 hi plane (rhh).
// GM 1 (layer 2): A1=meanbf(bf16), A2=rhh(bf16), W_r pre-scaled by BN (hi/lo),
//                 4 MFMAs/step, epilogue: +bias', L2norm, write fp32 d_out.
template <int GM>
__global__ __launch_bounds__(256, 2) void gemm_kernel(
    const u16* __restrict__ A1bf, const float* __restrict__ A2f,
    const u16* __restrict__ A2b,
    const u16* __restrict__ Wlh, const u16* __restrict__ Wll,
    const u16* __restrict__ Wrh, const u16* __restrict__ Wrl,
    const float* __restrict__ bias, float* __restrict__ outf,
    u16* __restrict__ outb, float* __restrict__ bnsums) {
    __shared__ float tile[4][16 * 132];
    __shared__ float ldsbn[256];
    const int tid = threadIdx.x;
    const int lane = tid & 63;
    const int wv = tid >> 6;
    const int col = lane & 15;
    const int quad = lane >> 4;
    if (GM == 0) ldsbn[tid] = 0.f;
    __syncthreads();

    const int nb0 = blockIdx.x * 256 + wv * 64;
    bool act[4];
    int tbc[4];  // clamped tile base (loads always in-bounds; MFMA on dup rows ok)
#pragma unroll
    for (int mt = 0; mt < 4; ++mt) {
        int tb = nb0 + mt * 16;
        act[mt] = (tb < N_NODES);
        tbc[mt] = act[mt] ? tb : (N_NODES - 16);
    }

    f32x4 acc[4][8];
#pragma unroll
    for (int mt = 0; mt < 4; ++mt)
#pragma unroll
        for (int ft = 0; ft < 8; ++ft) acc[mt][ft] = (f32x4){0.f, 0.f, 0.f, 0.f};

    const int wofs = col * 128 + quad * 8;

#pragma unroll
    for (int ks = 0; ks < 4; ++ks) {
        const int k0 = ks * 32 + quad * 8;
        frag8 a1[4];
        U8 a2h[4], a2l[4];
#pragma unroll
        for (int mt = 0; mt < 4; ++mt) {
            const int arow = tbc[mt] + col;
            a1[mt] = *(const frag8*)(A1bf + (size_t)arow * 128 + k0);
            if (GM == 0) {
                const float4* ap = (const float4*)(A2f + (size_t)arow * 128 + k0);
                float4 q0 = ap[0], q1 = ap[1];
                float av[8] = {q0.x, q0.y, q0.z, q0.w, q1.x, q1.y, q1.z, q1.w};
#pragma unroll
                for (int j = 0; j < 8; ++j) {
                    u16 h = f2bf(av[j]);
                    a2h[mt].h[j] = h;
                    a2l[mt].h[j] = f2bf(av[j] - bf2f(h));
                }
            } else {
                a2h[mt].f = *(const frag8*)(A2b + (size_t)arow * 128 + k0);
            }
        }
#pragma unroll
        for (int ft = 0; ft < 8; ++ft) {
            const int wo = ft * 2048 + ks * 32 + wofs;
            frag8 blh = *(const frag8*)(Wlh + wo);
            frag8 bll = *(const frag8*)(Wll + wo);
            frag8 brh = *(const frag8*)(Wrh + wo);
            frag8 brl = *(const frag8*)(Wrl + wo);
#pragma unroll
            for (int mt = 0; mt < 4; ++mt) {
                acc[mt][ft] = __builtin_amdgcn_mfma_f32_16x16x32_bf16(a1[mt], blh, acc[mt][ft], 0, 0, 0);
                acc[mt][ft] = __builtin_amdgcn_mfma_f32_16x16x32_bf16(a1[mt], bll, acc[mt][ft], 0, 0, 0);
                acc[mt][ft] = __builtin_amdgcn_mfma_f32_16x16x32_bf16(a2h[mt].f, brh, acc[mt][ft], 0, 0, 0);
                if (GM == 0)
                    acc[mt][ft] = __builtin_amdgcn_mfma_f32_16x16x32_bf16(a2l[mt].f, brh, acc[mt][ft], 0, 0, 0);
                acc[mt][ft] = __builtin_amdgcn_mfma_f32_16x16x32_bf16(a2h[mt].f, brl, acc[mt][ft], 0, 0, 0);
            }
        }
    }

    float bsv[8];
#pragma unroll
    for (int ft = 0; ft < 8; ++ft) bsv[ft] = bias[ft * 16 + col];

#pragma unroll
    for (int mt = 0; mt < 4; ++mt) {
        if (!act[mt]) continue;  // wave-uniform
        float ss[4] = {0.f, 0.f, 0.f, 0.f};
#pragma unroll
        for (int ft = 0; ft < 8; ++ft)
#pragma unroll
            for (int r = 0; r < 4; ++r) {
                float t = acc[mt][ft][r] + bsv[ft];
                acc[mt][ft][r] = t;
                ss[r] += t * t;
            }
#pragma unroll
        for (int m = 1; m <= 8; m <<= 1)
#pragma unroll
            for (int r = 0; r < 4; ++r) ss[r] += __shfl_xor(ss[r], m, 64);
        float invn[4];
#pragma unroll
        for (int r = 0; r < 4; ++r) invn[r] = 1.0f / fmaxf(sqrtf(ss[r]), 1e-12f);
#pragma unroll
        for (int ft = 0; ft < 8; ++ft)
#pragma unroll
            for (int r = 0; r < 4; ++r) {
                float t = acc[mt][ft][r] * invn[r];
                if (GM == 0) t = fmaxf(t, 0.f);
                acc[mt][ft][r] = t;
                tile[wv][(quad * 4 + r) * 132 + ft * 16 + col] = t;
            }
        if (GM == 0) {
#pragma unroll
            for (int ft = 0; ft < 8; ++ft) {
                float s1 = (acc[mt][ft][0] + acc[mt][ft][1]) + (acc[mt][ft][2] + acc[mt][ft][3]);
                float s2 = (acc[mt][ft][0] * acc[mt][ft][0] + acc[mt][ft][1] * acc[mt][ft][1]) +
                           (acc[mt][ft][2] * acc[mt][ft][2] + acc[mt][ft][3] * acc[mt][ft][3]);
                s1 += __shfl_xor(s1, 16, 64); s1 += __shfl_xor(s1, 32, 64);
                s2 += __shfl_xor(s2, 16, 64); s2 += __shfl_xor(s2, 32, 64);
                if (quad == 0) {
                    atomicAdd(&ldsbn[ft * 16 + col], s1);
                    atomicAdd(&ldsbn[128 + ft * 16 + col], s2);
                }
            }
        }
        asm volatile("s_waitcnt lgkmcnt(0)" ::: "memory");
        const int tb = nb0 + mt * 16;
        if (GM == 0) {
            u32* orow = (u32*)outb;
#pragma unroll
            for (int r = 0; r < 16; ++r) {
                float x0 = tile[wv][r * 132 + 2 * lane];
                float x1 = tile[wv][r * 132 + 2 * lane + 1];
                orow[(size_t)(tb + r) * 64 + lane] = packbf(x0, x1);
            }
        } else {
            float2* orow = (float2*)outf;
#pragma unroll
            for (int r = 0; r < 16; ++r) {
                float x0 = tile[wv][r * 132 + 2 * lane];
                float x1 = tile[wv][r * 132 + 2 * lane + 1];
                orow[(size_t)(tb + r) * 64 + lane] = make_float2(x0, x1);
            }
        }
        asm volatile("s_waitcnt lgkmcnt(0)" ::: "memory");
    }
    if (GM == 0) {
        __syncthreads();
        atomicAdd(&bnsums[tid], ldsbn[tid]);
    }
}

// ---------------- BN finalize: scale/shift from sums ----------------
__global__ void bnfin_kernel(const float* __restrict__ sums, const float* __restrict__ gamma,
                             const float* __restrict__ beta, float* __restrict__ bnp) {
    int f = threadIdx.x;
    if (f >= 128) return;
    const float invN = 1.0f / (float)N_NODES;
    float mu = sums[f] * invN;
    float var = sums[128 + f] * invN - mu * mu;
    float sc = gamma[f] * rsqrtf(fmaxf(var, 0.f) + 1e-5f);
    bnp[f] = sc;
    bnp[128 + f] = beta[f] - mu * sc;
}

// ---------------- layer-2 weight prep: Wr2' = s .* Wr2 (split), bias2' = b + Wr2@t ----
__global__ void wprep_kernel(const float* __restrict__ Wr2, const float* __restrict__ bl2,
                             const float* __restrict__ bnp, u16* __restrict__ wh,
                             u16* __restrict__ wl, float* __restrict__ bias2p) {
    __shared__ float p[2];
    const int f = blockIdx.x;
    const int k = threadIdx.x;  // 128 threads
    float w = Wr2[f * 128 + k];
    float contrib = w * bnp[128 + k];
    float v = w * bnp[k];
    u16 h = f2bf(v);
    wh[f * 128 + k] = h;
    wl[f * 128 + k] = f2bf(v - bf2f(h));
#pragma unroll
    for (int m = 1; m <= 32; m <<= 1) contrib += __shfl_xor(contrib, m, 64);
    if ((k & 63) == 0) p[k >> 6] = contrib;
    __syncthreads();
    if (k == 0) bias2p[f] = bl2[f] + p[0] + p[1];
}

extern "C" void kernel_launch(void* const* d_in, const int* in_sizes, int n_in,
                              void* d_out, int out_size, void* d_ws, size_t ws_size,
                              hipStream_t stream) {
    const int N = N_NODES;
    const int E = in_sizes[1] / 2;

    const float* x     = (const float*)d_in[0];
    const int*   ei    = (const int*)d_in[1];
    const float* Wl1   = (const float*)d_in[2];
    const float* bl1   = (const float*)d_in[3];
    const float* Wr1   = (const float*)d_in[4];
    const float* gamma = (const float*)d_in[5];
    const float* beta  = (const float*)d_in[6];
    const float* Wl2   = (const float*)d_in[7];
    const float* bl2   = (const float*)d_in[8];
    const float* Wr2   = (const float*)d_in[9];
    float* outp = (float*)d_out;

    char* ws = (char*)d_ws;
    size_t off = 0;
    auto alloc = [&](size_t b) { size_t r = off; off += (b + 255) & ~(size_t)255; return r; };
    int*   flag     = (int*)  (ws + alloc(4));
    int*   cnt      = (int*)  (ws + alloc((size_t)N * 4));
    int*   rowstart = (int*)  (ws + alloc((size_t)(N + 1) * 4));
    int*   partials = (int*)  (ws + alloc(4096));
    int*   csr      = (int*)  (ws + alloc((size_t)E * 4));
    float* bnsums   = (float*)(ws + alloc(256 * 4));
    float* bnp      = (float*)(ws + alloc(256 * 4));
    float* bias2p   = (float*)(ws + alloc(128 * 4));
    u16*   w1lh     = (u16*)  (ws + alloc(16384 * 2));
    u16*   w1ll     = (u16*)  (ws + alloc(16384 * 2));
    u16*   w1rh     = (u16*)  (ws + alloc(16384 * 2));
    u16*   w1rl     = (u16*)  (ws + alloc(16384 * 2));
    u16*   w2lh     = (u16*)  (ws + alloc(16384 * 2));
    u16*   w2ll     = (u16*)  (ws + alloc(16384 * 2));
    u16*   w2rsh    = (u16*)  (ws + alloc(16384 * 2));
    u16*   w2rsl    = (u16*)  (ws + alloc(16384 * 2));
    u16*   xh       = (u16*)  (ws + alloc((size_t)N * 128 * 2));
    u16*   meanbf   = (u16*)  (ws + alloc((size_t)N * 128 * 2));
    u16*   rhh      = (u16*)  (ws + alloc((size_t)N * 128 * 2));  // ~85 MB total

    hipMemsetAsync(cnt, 0, (size_t)N * 4, stream);
    hipMemsetAsync(bnsums, 0, 256 * 4, stream);

    detect_kernel<<<1, 64, 0, stream>>>(ei, flag, E);
    hist_kernel<<<(E + 255) / 256, 256, 0, stream>>>(ei, cnt, flag, E);
    const int nb = (N + 1023) / 1024;
    scan1_kernel<<<nb, 1024, 0, stream>>>(cnt, rowstart, partials, N);
    scan2_kernel<<<1, 1024, 0, stream>>>(partials, nb);
    scan3_kernel<<<nb, 1024, 0, stream>>>(rowstart, partials, N, E);
    scatter_kernel<<<(E + 255) / 256, 256, 0, stream>>>(ei, rowstart, cnt, csr, flag, E);

    wsplit_kernel<<<64, 256, 0, stream>>>(Wl1, w1lh, w1ll, 16384);
    wsplit_kernel<<<64, 256, 0, stream>>>(Wr1, w1rh, w1rl, 16384);
    wsplit_kernel<<<64, 256, 0, stream>>>(Wl2, w2lh, w2ll, 16384);
    xtobf_kernel<<<(N * 64 + 255) / 256, 256, 0, stream>>>(x, xh, N * 64);

    // conv1
    agg_kernel<0><<<(N + 3) / 4, 256, 0, stream>>>(xh, rowstart, csr, meanbf, nullptr);
    gemm_kernel<0><<<(N + 255) / 256, 256, 0, stream>>>(meanbf, x, nullptr,
                                                        w1lh, w1ll, w1rh, w1rl,
                                                        bl1, nullptr, rhh, bnsums);
    bnfin_kernel<<<1, 128, 0, stream>>>(bnsums, gamma, beta, bnp);
    wprep_kernel<<<128, 128, 0, stream>>>(Wr2, bl2, bnp, w2rsh, w2rsl, bias2p);
    // conv2
    agg_kernel<1><<<(N + 3) / 4, 256, 0, stream>>>(rhh, rowstart, csr, meanbf, bnp);
    gemm_kernel<1><<<(N + 255) / 256, 256, 0, stream>>>(meanbf, nullptr, rhh,
                                                        w2lh, w2ll, w2rsh, w2rsl,
                                                        bias2p, outp, nullptr, nullptr);
}

// Round 4
// 536.461 us; speedup vs baseline: 1.4568x; 1.0320x over previous
//
#include <hip/hip_runtime.h>

typedef unsigned short u16;
typedef unsigned int   u32;

#define N_NODES 100000
#define CHUNK_E 8192

typedef short frag8 __attribute__((ext_vector_type(8)));
typedef float f32x4 __attribute__((ext_vector_type(4)));

__device__ __forceinline__ float bf2f(u16 h) {
    union { u32 u; float f; } c; c.u = ((u32)h) << 16; return c.f;
}
__device__ __forceinline__ u16 f2bf(float f) {
    union { float f; u32 u; } c; c.f = f;
    u32 u = c.u;
    return (u16)((u + 0x7FFFu + ((u >> 16) & 1u)) >> 16);
}
__device__ __forceinline__ float2 bfx2(u32 u) {
    union { u32 u; float f; } lo, hi;
    lo.u = u << 16; hi.u = u & 0xFFFF0000u;
    return make_float2(lo.f, hi.f);
}
__device__ __forceinline__ u32 packbf(float a, float b) {
    return (u32)f2bf(a) | ((u32)f2bf(b) << 16);
}

union U8 { frag8 f; u16 h[8]; };

// ---------------- edge-index layout detect (int32 vs int64) ----------------
__global__ void detect_kernel(const int* __restrict__ ei, int* __restrict__ flag, int E) {
    int any = 0;
    int lim = min(2048, 2 * E);
    for (int i = 1 + 2 * (int)threadIdx.x; i < lim; i += 128) any |= ei[i];
    unsigned long long b = __ballot(any != 0);
    if (threadIdx.x == 0) *flag = (b != 0ULL) ? 1 : 0;  // 1 => int32 layout
}

// ---------------- CSR build (XCD-partitioned: block b -> chunk b>>3, xcd b&7) ------
// Only edges with (dst>>12)&7 == xcd are handled by this block, so all atomics /
// csr-line writes for a given dst come from one XCD: no cross-XCD L2 line bounce.
__global__ __launch_bounds__(256) void hist_kernel(const int* __restrict__ ei,
                                                   int* __restrict__ cnt,
                                                   const int* __restrict__ flag, int E) {
    const int xcd = blockIdx.x & 7;
    const int base = (blockIdx.x >> 3) * CHUNK_E;
    const int is32 = *flag;
    for (int i = 0; i < CHUNK_E; i += 256) {
        int e = base + i + threadIdx.x;
        if (e < E) {
            int d = is32 ? ei[E + e] : ei[2 * (E + (long long)e)];
            if ((u32)d < (u32)N_NODES && ((d >> 12) & 7) == xcd)
                atomicAdd(&cnt[d], 1);
        }
    }
}

__global__ void scan1_kernel(const int* __restrict__ cnt, int* __restrict__ row,
                             int* __restrict__ part, int n) {
    __shared__ int lds[1024];
    int t = threadIdx.x, g = blockIdx.x * 1024 + t;
    int v = (g < n) ? cnt[g] : 0;
    lds[t] = v;
    __syncthreads();
    for (int off = 1; off < 1024; off <<= 1) {
        int x = (t >= off) ? lds[t - off] : 0;
        __syncthreads();
        lds[t] += x;
        __syncthreads();
    }
    if (g < n) row[g] = lds[t] - v;           // exclusive
    if (t == 1023) part[blockIdx.x] = lds[t]; // block total
}

__global__ void scan2_kernel(int* __restrict__ part, int nb) {
    __shared__ int lds[1024];
    int t = threadIdx.x;
    int v = (t < nb) ? part[t] : 0;
    lds[t] = v;
    __syncthreads();
    for (int off = 1; off < 1024; off <<= 1) {
        int x = (t >= off) ? lds[t - off] : 0;
        __syncthreads();
        lds[t] += x;
        __syncthreads();
    }
    if (t < nb) part[t] = lds[t] - v;
}

__global__ void scan3_kernel(int* __restrict__ row, const int* __restrict__ part,
                             int n, int E) {
    int g = blockIdx.x * 1024 + threadIdx.x;
    if (g < n) row[g] += part[blockIdx.x];
    if (g == 0) row[n] = E;
}

// uses cnt as the fill counter (atomicSub); cnt ends at 0 (re-memset next launch)
__global__ __launch_bounds__(256) void scatter_kernel(const int* __restrict__ ei,
                                                      const int* __restrict__ row,
                                                      int* __restrict__ cnt,
                                                      int* __restrict__ csr,
                                                      const int* __restrict__ flag, int E) {
    const int xcd = blockIdx.x & 7;
    const int base = (blockIdx.x >> 3) * CHUNK_E;
    const int is32 = *flag;
    for (int i = 0; i < CHUNK_E; i += 256) {
        int e = base + i + threadIdx.x;
        if (e < E) {
            int d = is32 ? ei[E + e] : ei[2 * (E + (long long)e)];
            if ((u32)d < (u32)N_NODES && ((d >> 12) & 7) == xcd) {
                int s = is32 ? ei[e] : ei[2 * (long long)e];
                int idx = atomicSub(&cnt[d], 1) - 1;
                csr[row[d] + idx] = ((u32)s < (u32)N_NODES) ? s : 0;
            }
        }
    }
}

// ---------------- weight split: W(fp32) -> bf16 hi + bf16 lo planes ----------------
__global__ void wsplit_kernel(const float* __restrict__ W, u16* __restrict__ hi,
                              u16* __restrict__ lo, int n) {
    int i = blockIdx.x * 256 + threadIdx.x;
    if (i >= n) return;
    float v = W[i];
    u16 h = f2bf(v);
    hi[i] = h;
    lo[i] = f2bf(v - bf2f(h));
}

// ---------------- x -> bf16 hi plane (gather source) ----------------
__global__ void xtobf_kernel(const float* __restrict__ X, u16* __restrict__ out, int n2) {
    int i = blockIdx.x * 256 + threadIdx.x;
    if (i >= n2) return;
    float2 v = ((const float2*)X)[i];
    ((u32*)out)[i] = packbf(v.x, v.y);
}

// ---------------- mean aggregation over CSR (bf16 rows -> bf16 mean) ----------------
// Wave = 1 dst node; lane = g*16+l: neighbor slot g (4 in flight), feat slice l (8
// feats via uint4 = 16B/lane). MODE 0: plain mean. MODE 1: BN affine, deg==0 -> 0.
template <int MODE>
__global__ __launch_bounds__(256) void agg_kernel(
    const u16* __restrict__ X, const int* __restrict__ rowstart,
    const int* __restrict__ csr, u16* __restrict__ out,
    const float* __restrict__ bnp) {
    const int wid = (blockIdx.x * 256 + threadIdx.x) >> 6;
    const int lane = threadIdx.x & 63;
    const int g = lane >> 4;
    const int l = lane & 15;
    if (wid >= N_NODES) return;
    const int s = rowstart[wid];
    const int e = rowstart[wid + 1];
    const int deg = e - s;
    const uint4* Xv = (const uint4*)X;  // row = 16 uint4
    float av[8] = {0.f, 0.f, 0.f, 0.f, 0.f, 0.f, 0.f, 0.f};
    for (int i = s; i < e; i += 4) {
        if (g < e - i) {
            int idx = csr[i + g];
            uint4 q = Xv[(size_t)idx * 16 + l];
            float2 p0 = bfx2(q.x), p1 = bfx2(q.y), p2 = bfx2(q.z), p3 = bfx2(q.w);
            av[0] += p0.x; av[1] += p0.y; av[2] += p1.x; av[3] += p1.y;
            av[4] += p2.x; av[5] += p2.y; av[6] += p3.x; av[7] += p3.y;
        }
    }
#pragma unroll
    for (int j = 0; j < 8; ++j) {
        av[j] += __shfl_xor(av[j], 16, 64);
        av[j] += __shfl_xor(av[j], 32, 64);
    }
    if (g == 0) {
        const float inv = 1.0f / (float)max(deg, 1);
#pragma unroll
        for (int j = 0; j < 8; ++j) av[j] *= inv;
        if (MODE == 1) {
            if (deg > 0) {
#pragma unroll
                for (int j = 0; j < 8; ++j)
                    av[j] = av[j] * bnp[l * 8 + j] + bnp[128 + l * 8 + j];
            } else {
#pragma unroll
                for (int j = 0; j < 8; ++j) av[j] = 0.f;
            }
        }
        uint4 o;
        o.x = packbf(av[0], av[1]); o.y = packbf(av[2], av[3]);
        o.z = packbf(av[4], av[5]); o.w = packbf(av[6], av[7]);
        ((uint4*)out)[(size_t)wid * 16 + l] = o;
    }
}

// ---------------- fused GEMM with 4x weight reuse (MT=4 node tiles / wave) --------
// GM 0 (layer 1): A1=meanbf(bf16), A2=x(fp32, split in VALU), 5 MFMAs/step,
//                 epilogue: +bias, L2norm, ReLU, BN sums, write bf16 hi plane (rhh).
// GM 1 (layer 2): A1=meanbf(bf16), A2=rhh(bf16), W_r pre-scaled by BN (hi/lo),
//                 4 MFMAs/step, epilogue: +bias', L2norm, write fp32 d_out.
template <int GM>
__global__ __launch_bounds__(256, 2) void gemm_kernel(
    const u16* __restrict__ A1bf, const float* __restrict__ A2f,
    const u16* __restrict__ A2b,
    const u16* __restrict__ Wlh, const u16* __restrict__ Wll,
    const u16* __restrict__ Wrh, const u16* __restrict__ Wrl,
    const float* __restrict__ bias, float* __restrict__ outf,
    u16* __restrict__ outb, float* __restrict__ bnsums) {
    __shared__ float tile[4][16 * 132];
    __shared__ float ldsbn[256];
    const int tid = threadIdx.x;
    const int lane = tid & 63;
    const int wv = tid >> 6;
    const int col = lane & 15;
    const int quad = lane >> 4;
    if (GM == 0) ldsbn[tid] = 0.f;
    __syncthreads();

    const int nb0 = blockIdx.x * 256 + wv * 64;
    bool act[4];
    int tbc[4];  // clamped tile base (loads always in-bounds; MFMA on dup rows ok)
#pragma unroll
    for (int mt = 0; mt < 4; ++mt) {
        int tb = nb0 + mt * 16;
        act[mt] = (tb < N_NODES);
        tbc[mt] = act[mt] ? tb : (N_NODES - 16);
    }

    f32x4 acc[4][8];
#pragma unroll
    for (int mt = 0; mt < 4; ++mt)
#pragma unroll
        for (int ft = 0; ft < 8; ++ft) acc[mt][ft] = (f32x4){0.f, 0.f, 0.f, 0.f};

    const int wofs = col * 128 + quad * 8;

#pragma unroll
    for (int ks = 0; ks < 4; ++ks) {
        const int k0 = ks * 32 + quad * 8;
        frag8 a1[4];
        U8 a2h[4], a2l[4];
#pragma unroll
        for (int mt = 0; mt < 4; ++mt) {
            const int arow = tbc[mt] + col;
            a1[mt] = *(const frag8*)(A1bf + (size_t)arow * 128 + k0);
            if (GM == 0) {
                const float4* ap = (const float4*)(A2f + (size_t)arow * 128 + k0);
                float4 q0 = ap[0], q1 = ap[1];
                float av[8] = {q0.x, q0.y, q0.z, q0.w, q1.x, q1.y, q1.z, q1.w};
#pragma unroll
                for (int j = 0; j < 8; ++j) {
                    u16 h = f2bf(av[j]);
                    a2h[mt].h[j] = h;
                    a2l[mt].h[j] = f2bf(av[j] - bf2f(h));
                }
            } else {
                a2h[mt].f = *(const frag8*)(A2b + (size_t)arow * 128 + k0);
            }
        }
#pragma unroll
        for (int ft = 0; ft < 8; ++ft) {
            const int wo = ft * 2048 + ks * 32 + wofs;
            frag8 blh = *(const frag8*)(Wlh + wo);
            frag8 bll = *(const frag8*)(Wll + wo);
            frag8 brh = *(const frag8*)(Wrh + wo);
            frag8 brl = *(const frag8*)(Wrl + wo);
#pragma unroll
            for (int mt = 0; mt < 4; ++mt) {
                acc[mt][ft] = __builtin_amdgcn_mfma_f32_16x16x32_bf16(a1[mt], blh, acc[mt][ft], 0, 0, 0);
                acc[mt][ft] = __builtin_amdgcn_mfma_f32_16x16x32_bf16(a1[mt], bll, acc[mt][ft], 0, 0, 0);
                acc[mt][ft] = __builtin_amdgcn_mfma_f32_16x16x32_bf16(a2h[mt].f, brh, acc[mt][ft], 0, 0, 0);
                if (GM == 0)
                    acc[mt][ft] = __builtin_amdgcn_mfma_f32_16x16x32_bf16(a2l[mt].f, brh, acc[mt][ft], 0, 0, 0);
                acc[mt][ft] = __builtin_amdgcn_mfma_f32_16x16x32_bf16(a2h[mt].f, brl, acc[mt][ft], 0, 0, 0);
            }
        }
    }

    float bsv[8];
#pragma unroll
    for (int ft = 0; ft < 8; ++ft) bsv[ft] = bias[ft * 16 + col];

#pragma unroll
    for (int mt = 0; mt < 4; ++mt) {
        if (!act[mt]) continue;  // wave-uniform
        float ss[4] = {0.f, 0.f, 0.f, 0.f};
#pragma unroll
        for (int ft = 0; ft < 8; ++ft)
#pragma unroll
            for (int r = 0; r < 4; ++r) {
                float t = acc[mt][ft][r] + bsv[ft];
                acc[mt][ft][r] = t;
                ss[r] += t * t;
            }
#pragma unroll
        for (int m = 1; m <= 8; m <<= 1)
#pragma unroll
            for (int r = 0; r < 4; ++r) ss[r] += __shfl_xor(ss[r], m, 64);
        float invn[4];
#pragma unroll
        for (int r = 0; r < 4; ++r) invn[r] = 1.0f / fmaxf(sqrtf(ss[r]), 1e-12f);
#pragma unroll
        for (int ft = 0; ft < 8; ++ft)
#pragma unroll
            for (int r = 0; r < 4; ++r) {
                float t = acc[mt][ft][r] * invn[r];
                if (GM == 0) t = fmaxf(t, 0.f);
                acc[mt][ft][r] = t;
                tile[wv][(quad * 4 + r) * 132 + ft * 16 + col] = t;
            }
        if (GM == 0) {
#pragma unroll
            for (int ft = 0; ft < 8; ++ft) {
                float s1 = (acc[mt][ft][0] + acc[mt][ft][1]) + (acc[mt][ft][2] + acc[mt][ft][3]);
                float s2 = (acc[mt][ft][0] * acc[mt][ft][0] + acc[mt][ft][1] * acc[mt][ft][1]) +
                           (acc[mt][ft][2] * acc[mt][ft][2] + acc[mt][ft][3] * acc[mt][ft][3]);
                s1 += __shfl_xor(s1, 16, 64); s1 += __shfl_xor(s1, 32, 64);
                s2 += __shfl_xor(s2, 16, 64); s2 += __shfl_xor(s2, 32, 64);
                if (quad == 0) {
                    atomicAdd(&ldsbn[ft * 16 + col], s1);
                    atomicAdd(&ldsbn[128 + ft * 16 + col], s2);
                }
            }
        }
        asm volatile("s_waitcnt lgkmcnt(0)" ::: "memory");
        const int tb = nb0 + mt * 16;
        if (GM == 0) {
            u32* orow = (u32*)outb;
#pragma unroll
            for (int r = 0; r < 16; ++r) {
                float x0 = tile[wv][r * 132 + 2 * lane];
                float x1 = tile[wv][r * 132 + 2 * lane + 1];
                orow[(size_t)(tb + r) * 64 + lane] = packbf(x0, x1);
            }
        } else {
            float2* orow = (float2*)outf;
#pragma unroll
            for (int r = 0; r < 16; ++r) {
                float x0 = tile[wv][r * 132 + 2 * lane];
                float x1 = tile[wv][r * 132 + 2 * lane + 1];
                orow[(size_t)(tb + r) * 64 + lane] = make_float2(x0, x1);
            }
        }
        asm volatile("s_waitcnt lgkmcnt(0)" ::: "memory");
    }
    if (GM == 0) {
        __syncthreads();
        atomicAdd(&bnsums[tid], ldsbn[tid]);
    }
}

// ---------------- BN finalize: scale/shift from sums ----------------
__global__ void bnfin_kernel(const float* __restrict__ sums, const float* __restrict__ gamma,
                             const float* __restrict__ beta, float* __restrict__ bnp) {
    int f = threadIdx.x;
    if (f >= 128) return;
    const float invN = 1.0f / (float)N_NODES;
    float mu = sums[f] * invN;
    float var = sums[128 + f] * invN - mu * mu;
    float sc = gamma[f] * rsqrtf(fmaxf(var, 0.f) + 1e-5f);
    bnp[f] = sc;
    bnp[128 + f] = beta[f] - mu * sc;
}

// ---------------- layer-2 weight prep: Wr2' = s .* Wr2 (split), bias2' = b + Wr2@t ----
__global__ void wprep_kernel(const float* __restrict__ Wr2, const float* __restrict__ bl2,
                             const float* __restrict__ bnp, u16* __restrict__ wh,
                             u16* __restrict__ wl, float* __restrict__ bias2p) {
    __shared__ float p[2];
    const int f = blockIdx.x;
    const int k = threadIdx.x;  // 128 threads
    float w = Wr2[f * 128 + k];
    float contrib = w * bnp[128 + k];
    float v = w * bnp[k];
    u16 h = f2bf(v);
    wh[f * 128 + k] = h;
    wl[f * 128 + k] = f2bf(v - bf2f(h));
#pragma unroll
    for (int m = 1; m <= 32; m <<= 1) contrib += __shfl_xor(contrib, m, 64);
    if ((k & 63) == 0) p[k >> 6] = contrib;
    __syncthreads();
    if (k == 0) bias2p[f] = bl2[f] + p[0] + p[1];
}

extern "C" void kernel_launch(void* const* d_in, const int* in_sizes, int n_in,
                              void* d_out, int out_size, void* d_ws, size_t ws_size,
                              hipStream_t stream) {
    const int N = N_NODES;
    const int E = in_sizes[1] / 2;

    const float* x     = (const float*)d_in[0];
    const int*   ei    = (const int*)d_in[1];
    const float* Wl1   = (const float*)d_in[2];
    const float* bl1   = (const float*)d_in[3];
    const float* Wr1   = (const float*)d_in[4];
    const float* gamma = (const float*)d_in[5];
    const float* beta  = (const float*)d_in[6];
    const float* Wl2   = (const float*)d_in[7];
    const float* bl2   = (const float*)d_in[8];
    const float* Wr2   = (const float*)d_in[9];
    float* outp = (float*)d_out;

    char* ws = (char*)d_ws;
    size_t off = 0;
    auto alloc = [&](size_t b) { size_t r = off; off += (b + 255) & ~(size_t)255; return r; };
    int*   flag     = (int*)  (ws + alloc(4));
    int*   cnt      = (int*)  (ws + alloc((size_t)N * 4));
    int*   rowstart = (int*)  (ws + alloc((size_t)(N + 1) * 4));
    int*   partials = (int*)  (ws + alloc(4096));
    int*   csr      = (int*)  (ws + alloc((size_t)E * 4));
    float* bnsums   = (float*)(ws + alloc(256 * 4));
    float* bnp      = (float*)(ws + alloc(256 * 4));
    float* bias2p   = (float*)(ws + alloc(128 * 4));
    u16*   w1lh     = (u16*)  (ws + alloc(16384 * 2));
    u16*   w1ll     = (u16*)  (ws + alloc(16384 * 2));
    u16*   w1rh     = (u16*)  (ws + alloc(16384 * 2));
    u16*   w1rl     = (u16*)  (ws + alloc(16384 * 2));
    u16*   w2lh     = (u16*)  (ws + alloc(16384 * 2));
    u16*   w2ll     = (u16*)  (ws + alloc(16384 * 2));
    u16*   w2rsh    = (u16*)  (ws + alloc(16384 * 2));
    u16*   w2rsl    = (u16*)  (ws + alloc(16384 * 2));
    u16*   xh       = (u16*)  (ws + alloc((size_t)N * 128 * 2));
    u16*   meanbf   = (u16*)  (ws + alloc((size_t)N * 128 * 2));
    u16*   rhh      = (u16*)  (ws + alloc((size_t)N * 128 * 2));  // ~85 MB total

    hipMemsetAsync(cnt, 0, (size_t)N * 4, stream);
    hipMemsetAsync(bnsums, 0, 256 * 4, stream);

    const int echunks = (E + CHUNK_E - 1) / CHUNK_E;
    detect_kernel<<<1, 64, 0, stream>>>(ei, flag, E);
    hist_kernel<<<echunks * 8, 256, 0, stream>>>(ei, cnt, flag, E);
    const int nb = (N + 1023) / 1024;
    scan1_kernel<<<nb, 1024, 0, stream>>>(cnt, rowstart, partials, N);
    scan2_kernel<<<1, 1024, 0, stream>>>(partials, nb);
    scan3_kernel<<<nb, 1024, 0, stream>>>(rowstart, partials, N, E);
    scatter_kernel<<<echunks * 8, 256, 0, stream>>>(ei, rowstart, cnt, csr, flag, E);

    wsplit_kernel<<<64, 256, 0, stream>>>(Wl1, w1lh, w1ll, 16384);
    wsplit_kernel<<<64, 256, 0, stream>>>(Wr1, w1rh, w1rl, 16384);
    wsplit_kernel<<<64, 256, 0, stream>>>(Wl2, w2lh, w2ll, 16384);
    xtobf_kernel<<<(N * 64 + 255) / 256, 256, 0, stream>>>(x, xh, N * 64);

    // conv1
    agg_kernel<0><<<(N + 3) / 4, 256, 0, stream>>>(xh, rowstart, csr, meanbf, nullptr);
    gemm_kernel<0><<<(N + 255) / 256, 256, 0, stream>>>(meanbf, x, nullptr,
                                                        w1lh, w1ll, w1rh, w1rl,
                                                        bl1, nullptr, rhh, bnsums);
    bnfin_kernel<<<1, 128, 0, stream>>>(bnsums, gamma, beta, bnp);
    wprep_kernel<<<128, 128, 0, stream>>>(Wr2, bl2, bnp, w2rsh, w2rsl, bias2p);
    // conv2
    agg_kernel<1><<<(N + 3) / 4, 256, 0, stream>>>(rhh, rowstart, csr, meanbf, bnp);
    gemm_kernel<1><<<(N + 255) / 256, 256, 0, stream>>>(meanbf, nullptr, rhh,
                                                        w2lh, w2ll, w2rsh, w2rsl,
                                                        bias2p, outp, nullptr, nullptr);
}